// Round 5
// baseline (103.577 us; speedup 1.0000x reference)
//
#include <hip/hip_runtime.h>

typedef __attribute__((ext_vector_type(8))) short short8;   // 8 bf16 = 4 VGPR (MFMA A/B frag)
typedef __attribute__((ext_vector_type(4))) float f32x4;    // MFMA C/D frag
typedef __attribute__((ext_vector_type(4))) int   i32x4;

#define SDIM 32
#define HDIM 34
#define NEXP 12
#define ACOL 256
#define SPB  256
#define MAXROWS 432   // sum of per-expert 16-padded counts <= 256 + 12*15 = 436 -> last tile partial; 432 rows of storage is NOT enough
// NOTE: max padded rows = 256 + 12*15 = 436; round up to 448 for safety.
#undef  MAXROWS
#define MAXROWS 448

// fp32 -> bf16 (round-to-nearest-ish), pack two into one dword
__device__ __forceinline__ unsigned int bpack(float lo, float hi) {
    unsigned int a = __builtin_bit_cast(unsigned int, lo);
    unsigned int b = __builtin_bit_cast(unsigned int, hi);
    return ((a + 0x8000u) >> 16) | ((b + 0x8000u) & 0xffff0000u);
}

__global__ __launch_bounds__(256, 4) void actor_kernel(
    const float* __restrict__ states,
    const int*   __restrict__ epoch_idx,
    const float* __restrict__ W1,
    const float* __restrict__ b1,
    const float* __restrict__ Wout,
    const float* __restrict__ bout,
    const int*   __restrict__ mask,
    float*       __restrict__ out,
    int nB)
{
    // xs: 64 B/row = bf16 k0..31, XOR-swizzled 16B chunks; k32,33 live in xt.
    __shared__ __align__(16) unsigned int xs[MAXROWS * 16];  // 28672 B
    __shared__ unsigned int   xt[MAXROWS];                   // 1792 B (bf16 pair k32,33)
    __shared__ unsigned short rowid[MAXROWS];                // 896 B
    __shared__ float w1s[HDIM * SDIM];                       // 4352 B
    __shared__ float b1s[HDIM];
    __shared__ int   cnt[NEXP], goff[NEXP], ntl[NEXP];
    // total ~36 KB -> 4 blocks/CU

    const int t  = threadIdx.x;
    const int s0 = blockIdx.x * SPB;

    // ---- phase 0: stage W1/b1, zero counters, sentinel rowid ----
    for (int i = t; i < HDIM * SDIM; i += 256) w1s[i] = W1[i];
    if (t < HDIM) b1s[t] = b1[t];
    if (t < NEXP) cnt[t] = 0;
    for (int i = t; i < MAXROWS; i += 256) rowid[i] = 0xFFFFu;

    const int  sidx  = s0 + t;
    const bool valid = (sidx < nB);
    float sr[SDIM];
    int e = 0;
    if (valid) {
        const f32x4* sp = (const f32x4*)(states + (size_t)sidx * SDIM);
        #pragma unroll
        for (int q = 0; q < SDIM / 4; ++q) {
            f32x4 v = sp[q];
            sr[4*q+0] = v[0]; sr[4*q+1] = v[1]; sr[4*q+2] = v[2]; sr[4*q+3] = v[3];
        }
        e = epoch_idx[sidx];
    }
    __syncthreads();                 // cnt zeroed before atomics

    int rank = 0;
    if (valid) rank = atomicAdd(&cnt[e], 1);
    __syncthreads();                 // cnt final

    // ---- t0: exclusive scan into padded bases; everyone: trunk GEMV ----
    if (t == 0) {
        int base = 0;
        #pragma unroll
        for (int i = 0; i < NEXP; ++i) {
            goff[i] = base;
            int nt = (cnt[i] + 15) >> 4;
            ntl[i] = nt;
            base += nt << 4;
        }
    }
    float x[HDIM];
    if (valid) {
        #pragma unroll 2
        for (int h = 0; h < HDIM; ++h) {
            float acc = b1s[h];
            const float4* wr = (const float4*)(w1s + h * SDIM);
            #pragma unroll
            for (int q = 0; q < SDIM / 4; ++q) {
                float4 wv = wr[q];
                acc = fmaf(sr[4*q+0], wv.x, acc);
                acc = fmaf(sr[4*q+1], wv.y, acc);
                acc = fmaf(sr[4*q+2], wv.z, acc);
                acc = fmaf(sr[4*q+3], wv.w, acc);
            }
            x[h] = fmaxf(acc, 0.0f);
        }
    }
    __syncthreads();                 // goff ready

    // ---- phase 2: write bf16 x row into sorted+padded slot ----
    if (valid) {
        const int slot = goff[e] + rank;
        const unsigned swz = (unsigned)(slot & 3) << 4;
        char* rbase = (char*)xs + slot * 64;
        unsigned d[16];
        #pragma unroll
        for (int k = 0; k < 16; ++k) d[k] = bpack(x[2*k], x[2*k+1]);
        #pragma unroll
        for (int c = 0; c < 4; ++c) {
            f32x4 q;
            q[0] = __builtin_bit_cast(float, d[4*c+0]);
            q[1] = __builtin_bit_cast(float, d[4*c+1]);
            q[2] = __builtin_bit_cast(float, d[4*c+2]);
            q[3] = __builtin_bit_cast(float, d[4*c+3]);
            *(f32x4*)(rbase + (((unsigned)(c * 16)) ^ swz)) = q;
        }
        xt[slot]    = bpack(x[32], x[33]);
        rowid[slot] = (unsigned short)t;
    }
    __syncthreads();                 // xs/xt/rowid visible

    // ---- phase 3: swapped-operand MFMA, direct coalesced dwordx4 stores ----
    // D = Wfrag * xfrag: D col (lane&15) = state row r, D row (4g+reg) = action.
    const int wv   = t >> 6;
    const int lane = t & 63;
    const int r    = lane & 15;      // state row within tile (A... B-col) & W A-frag row sel
    const int g    = lane >> 4;      // k-group
    const int cb0  = wv * 64 + 4 * g;   // this lane's action column base (j adds 16)
    const float NEG = -1e9f;
    const float INF = __builtin_bit_cast(float, 0x7f800000u);

    // mask -> fminf operand: +INF keeps value, -1e9 forces masked
    f32x4 mf[4];
    #pragma unroll
    for (int j = 0; j < 4; ++j) {
        i32x4 mq = *(const i32x4*)(mask + cb0 + 16 * j);
        mf[j][0] = mq[0] ? INF : NEG;
        mf[j][1] = mq[1] ? INF : NEG;
        mf[j][2] = mq[2] ? INF : NEG;
        mf[j][3] = mq[3] ? INF : NEG;
    }

    float* outb = out + (size_t)s0 * ACOL;

    for (int e2 = 0; e2 < NEXP; ++e2) {
        const int ntiles = ntl[e2];
        if (ntiles == 0) continue;

        // W fragments (A operand): lane holds W[action = wv*64+16j+r][k=8g..8g+7]
        short8   bf1[4];
        unsigned w2[4];              // bf16 pair W[col][32,33], g==0 lanes only
        f32x4    bv[4];              // bias for this lane's 4 actions per j
        #pragma unroll
        for (int j = 0; j < 4; ++j) {
            const int col = wv * 64 + j * 16 + r;
            const float* wr = Wout + ((size_t)e2 * ACOL + col) * HDIM;
            const float2* wp = (const float2*)(wr + g * 8);
            float2 p0 = wp[0], p1 = wp[1], p2 = wp[2], p3 = wp[3];
            uint4 q1 = make_uint4(bpack(p0.x, p0.y), bpack(p1.x, p1.y),
                                  bpack(p2.x, p2.y), bpack(p3.x, p3.y));
            bf1[j] = __builtin_bit_cast(short8, q1);
            w2[j]  = (g == 0) ? bpack(wr[32], wr[33]) : 0u;
            bv[j]  = *(const f32x4*)(bout + e2 * ACOL + cb0 + 16 * j);
        }

        const int tb = goff[e2];
        for (int st = 0; st < ntiles; ++st) {
            const int row = tb + (st << 4) + r;
            const char* rp = (const char*)xs + row * 64;
            short8 a1 = *(const short8*)(rp + (((unsigned)(g * 16)) ^ ((unsigned)(row & 3) << 4)));
            const unsigned xtv = xt[row];
            const unsigned rid = rowid[row];
            short8 a2 = __builtin_bit_cast(short8,
                          make_uint4(g == 0 ? xtv : 0u, 0u, 0u, 0u));

            f32x4 acc[4];
            #pragma unroll
            for (int j = 0; j < 4; ++j) {
                f32x4 a = bv[j];
                a = __builtin_amdgcn_mfma_f32_16x16x32_bf16(bf1[j], a1, a, 0, 0, 0);
                short8 b2 = __builtin_bit_cast(short8,
                              make_uint4(w2[j], 0u, 0u, 0u));
                a = __builtin_amdgcn_mfma_f32_16x16x32_bf16(b2, a2, a, 0, 0, 0);
                acc[j] = a;
            }

            if (rid != 0xFFFFu) {
                float* ob = outb + (size_t)rid * ACOL + cb0;
                #pragma unroll
                for (int j = 0; j < 4; ++j) {
                    f32x4 v = acc[j];
                    v[0] = fminf(v[0], mf[j][0]);
                    v[1] = fminf(v[1], mf[j][1]);
                    v[2] = fminf(v[2], mf[j][2]);
                    v[3] = fminf(v[3], mf[j][3]);
                    *(f32x4*)(ob + 16 * j) = v;
                }
            }
        }
    }
}

extern "C" void kernel_launch(void* const* d_in, const int* in_sizes, int n_in,
                              void* d_out, int out_size, void* d_ws, size_t ws_size,
                              hipStream_t stream) {
    const float* states    = (const float*)d_in[0];
    const int*   epoch_idx = (const int*)  d_in[1];
    const float* W1        = (const float*)d_in[2];
    const float* b1        = (const float*)d_in[3];
    const float* Wout      = (const float*)d_in[4];
    const float* bout      = (const float*)d_in[5];
    const int*   mask      = (const int*)  d_in[6];
    float*       out       = (float*)d_out;

    const int nB   = in_sizes[0] / SDIM;
    const int grid = (nB + SPB - 1) / SPB;
    actor_kernel<<<grid, 256, 0, stream>>>(states, epoch_idx, W1, b1,
                                           Wout, bout, mask, out, nB);
}

// Round 6
// 101.064 us; speedup vs baseline: 1.0249x; 1.0249x over previous
//
#include <hip/hip_runtime.h>

typedef __attribute__((ext_vector_type(8))) short short8;   // 8 bf16 = 4 VGPR (MFMA A/B frag)
typedef __attribute__((ext_vector_type(4))) float f32x4;    // MFMA C/D frag
typedef __attribute__((ext_vector_type(4))) int   i32x4;

#define SDIM 32
#define HDIM 34
#define NEXP 12
#define ACOL 256
#define SPB  256
#define MAXROWS 448        // max padded rows = 256 + 12*15 = 436, round up
#define STG_STRIDE 260     // 16-row f32 staging, +4 pad: 2-way conflicts only (free)

// raw barriers: NEVER wait vmcnt -> global stores pipeline across tiles (T4)
#define BAR_RAW()  asm volatile("s_barrier" ::: "memory")
#define BAR_LGKM() asm volatile("s_waitcnt lgkmcnt(0)\n\ts_barrier" ::: "memory")

// fp32 -> bf16 (round-to-nearest-ish), pack two into one dword
__device__ __forceinline__ unsigned int bpack(float lo, float hi) {
    unsigned int a = __builtin_bit_cast(unsigned int, lo);
    unsigned int b = __builtin_bit_cast(unsigned int, hi);
    return ((a + 0x8000u) >> 16) | ((b + 0x8000u) & 0xffff0000u);
}

__global__ __launch_bounds__(256, 3) void actor_kernel(
    const float* __restrict__ states,
    const int*   __restrict__ epoch_idx,
    const float* __restrict__ W1,
    const float* __restrict__ b1,
    const float* __restrict__ Wout,
    const float* __restrict__ bout,
    const int*   __restrict__ mask,
    float*       __restrict__ out,
    int nB)
{
    // xs: 64 B/row = bf16 k0..31 in 4 16B chunks, chunk c stored at c^((row>>2)&3).
    // Per 16-row tile read: quad index (4r + g^(r>>2)) % 8 -> 8 quads x 2 lanes = free.
    __shared__ __align__(16) unsigned int xs[MAXROWS * 16];  // 28672 B
    __shared__ unsigned int   xt[MAXROWS];                   // 1792 B (bf16 pair k32,33)
    __shared__ unsigned short rowid[MAXROWS];                // 896 B
    __shared__ __align__(16) float stg[16 * STG_STRIDE];     // 16640 B; hosts w1s/b1s in phase 0-1
    __shared__ int cnt[NEXP], goff[NEXP], ntl[NEXP];
    // total ~48.2 KB -> 3 blocks/CU

    float* w1s = stg;                    // 1088 floats (phase 0-1 only)
    float* b1s = stg + HDIM * SDIM;      // 34 floats

    const int t  = threadIdx.x;
    const int s0 = blockIdx.x * SPB;

    // ---- phase 0: stage W1/b1, zero counters, sentinel rowid ----
    for (int i = t; i < HDIM * SDIM; i += 256) w1s[i] = W1[i];
    if (t < HDIM) b1s[t] = b1[t];
    if (t < NEXP) cnt[t] = 0;
    for (int i = t; i < MAXROWS; i += 256) rowid[i] = 0xFFFFu;

    const int  sidx  = s0 + t;
    const bool valid = (sidx < nB);
    float sr[SDIM];
    int e = 0;
    if (valid) {
        const f32x4* sp = (const f32x4*)(states + (size_t)sidx * SDIM);
        #pragma unroll
        for (int q = 0; q < SDIM / 4; ++q) {
            f32x4 v = sp[q];
            sr[4*q+0] = v[0]; sr[4*q+1] = v[1]; sr[4*q+2] = v[2]; sr[4*q+3] = v[3];
        }
        e = epoch_idx[sidx];
    }
    __syncthreads();                 // cnt zeroed, w1s staged

    int rank = 0;
    if (valid) rank = atomicAdd(&cnt[e], 1);
    __syncthreads();                 // cnt final

    // ---- t0: exclusive scan into 16-padded bases; everyone: trunk GEMV ----
    if (t == 0) {
        int base = 0;
        #pragma unroll
        for (int i = 0; i < NEXP; ++i) {
            goff[i] = base;
            int nt = (cnt[i] + 15) >> 4;
            ntl[i] = nt;
            base += nt << 4;
        }
    }
    float x[HDIM];
    if (valid) {
        #pragma unroll 2
        for (int h = 0; h < HDIM; ++h) {
            float acc = b1s[h];
            const float4* wr = (const float4*)(w1s + h * SDIM);
            #pragma unroll
            for (int q = 0; q < SDIM / 4; ++q) {
                float4 wv = wr[q];
                acc = fmaf(sr[4*q+0], wv.x, acc);
                acc = fmaf(sr[4*q+1], wv.y, acc);
                acc = fmaf(sr[4*q+2], wv.z, acc);
                acc = fmaf(sr[4*q+3], wv.w, acc);
            }
            x[h] = fmaxf(acc, 0.0f);
        }
    }
    __syncthreads();                 // goff ready

    // ---- phase 2: write bf16 x row into sorted+padded slot (swizzled) ----
    if (valid) {
        const int slot = goff[e] + rank;
        const unsigned sw = (((unsigned)slot >> 2) & 3u) << 4;
        char* rbase = (char*)xs + slot * 64;
        unsigned d[16];
        #pragma unroll
        for (int k = 0; k < 16; ++k) d[k] = bpack(x[2*k], x[2*k+1]);
        #pragma unroll
        for (int c = 0; c < 4; ++c) {
            f32x4 q;
            q[0] = __builtin_bit_cast(float, d[4*c+0]);
            q[1] = __builtin_bit_cast(float, d[4*c+1]);
            q[2] = __builtin_bit_cast(float, d[4*c+2]);
            q[3] = __builtin_bit_cast(float, d[4*c+3]);
            *(f32x4*)(rbase + (((unsigned)(c * 16)) ^ sw)) = q;
        }
        xt[slot]    = bpack(x[32], x[33]);
        rowid[slot] = (unsigned short)t;
    }
    __syncthreads();                 // xs/xt/rowid visible; last w1s use done

    // ---- phase 3: MFMA + staged transpose; raw barriers, stores never drained ----
    const int wv   = t >> 6;
    const int lane = t & 63;
    const int r    = lane & 15;      // state row in tile / B col (action within 16-tile)
    const int g    = lane >> 4;      // k-group
    const int colbase = wv * 64 + r;
    const float NEG = -1e9f;
    const i32x4 mq = *(const i32x4*)(mask + 4 * lane);   // mask for cols 4*lane..+3

    float* outb = out + (size_t)s0 * ACOL;

    for (int e2 = 0; e2 < NEXP; ++e2) {
        const int ntiles = ntl[e2];
        if (ntiles == 0) continue;

        // B-fragments (W) for this expert: 4 col-tiles, in registers
        short8   bf1[4];
        unsigned w2[4];
        float    bias[4];
        #pragma unroll
        for (int j = 0; j < 4; ++j) {
            const int col = colbase + j * 16;
            const float* wr = Wout + ((size_t)e2 * ACOL + col) * HDIM;
            const float2* wp = (const float2*)(wr + g * 8);
            float2 p0 = wp[0], p1 = wp[1], p2 = wp[2], p3 = wp[3];
            uint4 q1 = make_uint4(bpack(p0.x, p0.y), bpack(p1.x, p1.y),
                                  bpack(p2.x, p2.y), bpack(p3.x, p3.y));
            bf1[j] = __builtin_bit_cast(short8, q1);
            w2[j]  = (g == 0) ? bpack(wr[32], wr[33]) : 0u;
            bias[j] = bout[e2 * ACOL + col];
        }

        const int tb = goff[e2];
        for (int st = 0; st < ntiles; ++st) {
            const int rb  = tb + (st << 4);
            const int row = rb + r;
            const unsigned sw = (((unsigned)row >> 2) & 3u) << 4;
            const char* rp = (const char*)xs + row * 64;
            short8 a1 = *(const short8*)(rp + (((unsigned)(g * 16)) ^ sw));
            short8 a2 = __builtin_bit_cast(short8,
                          make_uint4(g == 0 ? xt[row] : 0u, 0u, 0u, 0u));

            f32x4 acc[4];
            #pragma unroll
            for (int j = 0; j < 4; ++j) {
                f32x4 a = {bias[j], bias[j], bias[j], bias[j]};
                a = __builtin_amdgcn_mfma_f32_16x16x32_bf16(a1, bf1[j], a, 0, 0, 0);
                short8 b2 = __builtin_bit_cast(short8,
                              make_uint4(w2[j], 0u, 0u, 0u));
                a = __builtin_amdgcn_mfma_f32_16x16x32_bf16(a2, b2, a, 0, 0, 0);
                acc[j] = a;
            }

            BAR_RAW();     // WAR: all waves done reading stg (prev tile). No vmcnt drain.
            #pragma unroll
            for (int j = 0; j < 4; ++j) {
                const int c = colbase + 16 * j;
                #pragma unroll
                for (int i = 0; i < 4; ++i)
                    stg[(g * 4 + i) * STG_STRIDE + c] = acc[j][i];
            }
            BAR_LGKM();    // RAW: staging visible. Still no vmcnt drain.

            // wave wv stores rows wv*4..wv*4+3, each one contiguous 1KB dwordx4 stream
            #pragma unroll
            for (int q = 0; q < 4; ++q) {
                const int lrow = wv * 4 + q;
                const unsigned rid = rowid[rb + lrow];
                f32x4 v = *(const f32x4*)&stg[lrow * STG_STRIDE + 4 * lane];
                v[0] = mq[0] ? v[0] : NEG;
                v[1] = mq[1] ? v[1] : NEG;
                v[2] = mq[2] ? v[2] : NEG;
                v[3] = mq[3] ? v[3] : NEG;
                if (rid != 0xFFFFu)
                    __builtin_nontemporal_store(v,
                        (f32x4*)(outb + (size_t)rid * ACOL + 4 * lane));
            }
        }
    }
}

extern "C" void kernel_launch(void* const* d_in, const int* in_sizes, int n_in,
                              void* d_out, int out_size, void* d_ws, size_t ws_size,
                              hipStream_t stream) {
    const float* states    = (const float*)d_in[0];
    const int*   epoch_idx = (const int*)  d_in[1];
    const float* W1        = (const float*)d_in[2];
    const float* b1        = (const float*)d_in[3];
    const float* Wout      = (const float*)d_in[4];
    const float* bout      = (const float*)d_in[5];
    const int*   mask      = (const int*)  d_in[6];
    float*       out       = (float*)d_out;

    const int nB   = in_sizes[0] / SDIM;
    const int grid = (nB + SPB - 1) / SPB;
    actor_kernel<<<grid, 256, 0, stream>>>(states, epoch_idx, W1, b1,
                                           Wout, bout, mask, out, nB);
}